// Round 1
// baseline (379.344 us; speedup 1.0000x reference)
//
#include <hip/hip_runtime.h>
#include <hip/hip_bf16.h>

typedef __attribute__((ext_vector_type(8))) short bf16x8;
typedef __attribute__((ext_vector_type(4))) float f32x4;
typedef __attribute__((ext_vector_type(4))) int int4v;

// Problem constants
#define NB 4
#define NN 4096
#define NC 256
// combined projection output columns: [0,32) q, [32,64) k, [64,320) v

__device__ __forceinline__ unsigned short f2bf(float f) {
    unsigned u = __builtin_bit_cast(unsigned, f);
    u += 0x7fffu + ((u >> 16) & 1u);   // round-to-nearest-even
    return (unsigned short)(u >> 16);
}

// ---------------- kernel 0: weight transpose + bf16 cast ----------------
// wt[c][k] = bf16(W[k][c]);  c: 0..31 wq, 32..63 wk, 64..319 wv
__global__ __launch_bounds__(256) void wt_kernel(
    const float* __restrict__ wq, const float* __restrict__ wk,
    const float* __restrict__ wv, unsigned short* __restrict__ wt)
{
    const int c = blockIdx.x;     // 0..319
    const int k = threadIdx.x;    // 0..255
    float v;
    if (c < 32)      v = wq[k * 32 + c];
    else if (c < 64) v = wk[k * 32 + (c - 32)];
    else             v = wv[k * 256 + (c - 64)];
    wt[c * 256 + k] = f2bf(v);
}

// ---------------- kernel 1: QKV projection (MFMA, no LDS) ----------------
// q_ws,k_ws: [16384][32] bf16 (natural).  vt_ws: [4][256][4096] bf16 (V transposed).
__global__ __launch_bounds__(256) void proj_kernel(
    const float* __restrict__ x,              // [16384][256]
    const unsigned short* __restrict__ wt,    // [320][256] = W^T bf16
    const float* __restrict__ bq, const float* __restrict__ bk,
    const float* __restrict__ bv,
    unsigned short* __restrict__ q_ws,
    unsigned short* __restrict__ k_ws,
    unsigned short* __restrict__ vt_ws)
{
    const int lane = threadIdx.x & 63;
    const int w    = threadIdx.x >> 6;
    const int l15  = lane & 15, hh = lane >> 4;
    const int m0   = blockIdx.x * 64 + w * 16;   // this wave's 16-row base

    f32x4 acc[20];
    #pragma unroll
    for (int i = 0; i < 20; ++i) acc[i] = f32x4{0.f, 0.f, 0.f, 0.f};

    const float* xrow = x + (size_t)(m0 + l15) * 256 + hh * 8;
    #pragma unroll
    for (int ks = 0; ks < 8; ++ks) {
        // A frag: x[m0+l15][ks*32 + hh*8 + j]  (fp32 -> bf16)
        float4 xa = ((const float4*)(xrow + ks * 32))[0];
        float4 xb = ((const float4*)(xrow + ks * 32))[1];
        bf16x8 afrag;
        afrag[0] = (short)f2bf(xa.x); afrag[1] = (short)f2bf(xa.y);
        afrag[2] = (short)f2bf(xa.z); afrag[3] = (short)f2bf(xa.w);
        afrag[4] = (short)f2bf(xb.x); afrag[5] = (short)f2bf(xb.y);
        afrag[6] = (short)f2bf(xb.z); afrag[7] = (short)f2bf(xb.w);
        #pragma unroll
        for (int ct = 0; ct < 20; ++ct) {
            // B frag: W[k][c] = wt[c][k], 8 contiguous k per lane (16B load)
            bf16x8 bfrag = *(const bf16x8*)(wt + (size_t)(ct * 16 + l15) * 256 + ks * 32 + hh * 8);
            acc[ct] = __builtin_amdgcn_mfma_f32_16x16x32_bf16(afrag, bfrag, acc[ct], 0, 0, 0);
        }
    }

    const int b    = m0 >> 12;
    const int nloc = m0 & 4095;
    #pragma unroll
    for (int ct = 0; ct < 20; ++ct) {
        const int c0 = ct * 16;
        float bias;
        if (c0 < 32)      bias = bq[c0 + l15];
        else if (c0 < 64) bias = bk[c0 - 32 + l15];
        else              bias = bv[c0 - 64 + l15];
        if (c0 < 64) {
            unsigned short* dst = (c0 < 32) ? q_ws : k_ws;
            const int cc = (c0 < 32) ? c0 : (c0 - 32);
            #pragma unroll
            for (int i = 0; i < 4; ++i)
                dst[(size_t)(m0 + hh * 4 + i) * 32 + cc + l15] = f2bf(acc[ct][i] + bias);
        } else {
            // vt[b][c][n], pack adjacent n pairs -> u32 stores
            const int cc = c0 - 64 + l15;
            #pragma unroll
            for (int i = 0; i < 4; i += 2) {
                unsigned lo = f2bf(acc[ct][i]     + bias);
                unsigned hi = f2bf(acc[ct][i + 1] + bias);
                *(unsigned*)(vt_ws + ((size_t)b * 256 + cc) * 4096 + nloc + hh * 4 + i)
                    = lo | (hi << 16);
            }
        }
    }
}

// ---------------- kernel 2: fused flash attention + residual ----------------
// 256 blocks = 4 batches x 64 q-tiles of 64 rows. 4 waves in 2(q)x2(c) split.
__global__ __launch_bounds__(256) void attn_kernel(
    const unsigned short* __restrict__ q_ws,
    const unsigned short* __restrict__ k_ws,
    const unsigned short* __restrict__ vt_ws,
    const float* __restrict__ x,
    const float* __restrict__ gamma_p,
    float* __restrict__ out)
{
    __shared__ unsigned short vt_lds[256 * 64];   // [c][key] rows of 128B, XOR-swizzled
    __shared__ unsigned short p_lds[2][32 * 64];  // per q-pair: [qrow][key], swizzled

    const int lane = threadIdx.x & 63;
    const int w    = threadIdx.x >> 6;
    const int l15  = lane & 15, hh = lane >> 4;
    const int b    = blockIdx.x >> 6;
    const int q0   = (blockIdx.x & 63) * 64;
    const int wq_  = w >> 1;            // q-pair id (0/1)
    const int wc_  = w & 1;             // c-half id (0/1)
    const int qbase = q0 + wq_ * 32;
    const int cbase = wc_ * 128;

    // Q A-frags (persistent): Q[qbase+qt*16+l15][hh*8+j]
    bf16x8 aq[2];
    #pragma unroll
    for (int qt = 0; qt < 2; ++qt)
        aq[qt] = *(const bf16x8*)(q_ws + (size_t)(b * 4096 + qbase + qt * 16 + l15) * 32 + hh * 8);

    f32x4 acc[2][8];
    float mrow[2][4], lp[2][4];
    #pragma unroll
    for (int qt = 0; qt < 2; ++qt) {
        #pragma unroll
        for (int ct = 0; ct < 8; ++ct) acc[qt][ct] = f32x4{0.f, 0.f, 0.f, 0.f};
        #pragma unroll
        for (int i = 0; i < 4; ++i) { mrow[qt][i] = -1e30f; lp[qt][i] = 0.f; }
    }

    const float gamma = gamma_p[0];

    for (int kt = 0; kt < 64; ++kt) {
        const int kb = kt * 64;
        __syncthreads();   // previous tile's LDS reads complete

        // ---- stage V^T tile: 256 c-rows x 64 keys bf16 = 32KB, swizzled ----
        {
            const unsigned short* src = vt_ws + (size_t)b * 256 * 4096 + kb;
            #pragma unroll
            for (int e = 0; e < 8; ++e) {
                int idx  = e * 256 + threadIdx.x;   // 0..2047 16B-chunks
                int c    = idx >> 3;
                int slot = idx & 7;
                int4v v = *(const int4v*)(src + (size_t)c * 4096 + slot * 8);
                *(int4v*)((char*)vt_lds + c * 128 + ((slot ^ (c & 7)) << 4)) = v;
            }
        }

        // ---- energy + online softmax (both waves of a q-pair compute identically) ----
        #pragma unroll
        for (int qt = 0; qt < 2; ++qt) {
            f32x4 e[4];
            #pragma unroll
            for (int g = 0; g < 4; ++g) {
                bf16x8 bk_ = *(const bf16x8*)(k_ws + (size_t)(b * 4096 + kb + g * 16 + l15) * 32 + hh * 8);
                f32x4 z = {0.f, 0.f, 0.f, 0.f};
                e[g] = __builtin_amdgcn_mfma_f32_16x16x32_bf16(aq[qt], bk_, z, 0, 0, 0);
            }
            #pragma unroll
            for (int i = 0; i < 4; ++i) {
                float mx = fmaxf(fmaxf(e[0][i], e[1][i]), fmaxf(e[2][i], e[3][i]));
                mx = fmaxf(mx, __shfl_xor(mx, 1));
                mx = fmaxf(mx, __shfl_xor(mx, 2));
                mx = fmaxf(mx, __shfl_xor(mx, 4));
                mx = fmaxf(mx, __shfl_xor(mx, 8));
                float mn   = fmaxf(mrow[qt][i], mx);
                float corr = __expf(mrow[qt][i] - mn);
                mrow[qt][i] = mn;
                float rs = 0.f;
                #pragma unroll
                for (int g = 0; g < 4; ++g) {
                    float p = __expf(e[g][i] - mn);
                    rs += p;
                    if (wc_ == 0) {   // one wave per pair writes P
                        int r   = qt * 16 + hh * 4 + i;
                        int off = g * 32 + l15 * 2;                 // byte within row
                        int sw  = ((((off >> 4) ^ (r & 7)) << 4)) | (off & 15);
                        *(unsigned short*)((char*)&p_lds[wq_][0] + r * 128 + sw) = f2bf(p);
                    }
                }
                lp[qt][i] = lp[qt][i] * corr + rs;   // lane-partial; reduced at the end
                #pragma unroll
                for (int ct = 0; ct < 8; ++ct) acc[qt][ct][i] *= corr;
            }
        }
        __syncthreads();   // V staged + P written

        // ---- PV: acc[qt][ct] += P[16x32] * V[32x16] ----
        #pragma unroll
        for (int qt = 0; qt < 2; ++qt) {
            bf16x8 ap[2];
            #pragma unroll
            for (int s = 0; s < 2; ++s) {
                int r   = qt * 16 + l15;
                int off = s * 64 + hh * 16;
                int sw  = ((off >> 4) ^ (r & 7)) << 4;
                ap[s] = *(const bf16x8*)((char*)&p_lds[wq_][0] + r * 128 + sw);
            }
            #pragma unroll
            for (int ct = 0; ct < 8; ++ct) {
                int c = cbase + ct * 16 + l15;
                #pragma unroll
                for (int s = 0; s < 2; ++s) {
                    int off = s * 64 + hh * 16;
                    int sw  = ((off >> 4) ^ (c & 7)) << 4;
                    bf16x8 bv_ = *(const bf16x8*)((char*)vt_lds + c * 128 + sw);
                    acc[qt][ct] = __builtin_amdgcn_mfma_f32_16x16x32_bf16(ap[s], bv_, acc[qt][ct], 0, 0, 0);
                }
            }
        }
    }

    // ---- epilogue: reduce l, out = gamma*(acc/l) + x ----
    #pragma unroll
    for (int qt = 0; qt < 2; ++qt) {
        #pragma unroll
        for (int i = 0; i < 4; ++i) {
            float s = lp[qt][i];
            s += __shfl_xor(s, 1); s += __shfl_xor(s, 2);
            s += __shfl_xor(s, 4); s += __shfl_xor(s, 8);
            float inv = 1.f / s;
            #pragma unroll
            for (int ct = 0; ct < 8; ++ct) {
                int n = qbase + qt * 16 + hh * 4 + i;
                int c = cbase + ct * 16 + l15;
                size_t idx = ((size_t)b * 4096 + n) * 256 + c;
                out[idx] = gamma * (acc[qt][ct][i] * inv) + x[idx];
            }
        }
    }
}

extern "C" void kernel_launch(void* const* d_in, const int* in_sizes, int n_in,
                              void* d_out, int out_size, void* d_ws, size_t ws_size,
                              hipStream_t stream) {
    const float* x     = (const float*)d_in[0];
    const float* wq    = (const float*)d_in[1];
    const float* bq    = (const float*)d_in[2];
    const float* wk    = (const float*)d_in[3];
    const float* bk    = (const float*)d_in[4];
    const float* wv    = (const float*)d_in[5];
    const float* bv    = (const float*)d_in[6];
    const float* gamma = (const float*)d_in[7];
    float* out = (float*)d_out;

    char* ws = (char*)d_ws;
    unsigned short* wt    = (unsigned short*)(ws);                         // 320*256*2 = 160KB
    unsigned short* q_ws  = (unsigned short*)(ws + 163840);                // 1MB
    unsigned short* k_ws  = (unsigned short*)(ws + 163840 + 1048576);      // 1MB
    unsigned short* vt_ws = (unsigned short*)(ws + 163840 + 2097152);      // 8MB

    wt_kernel  <<<320, 256, 0, stream>>>(wq, wk, wv, wt);
    proj_kernel<<<256, 256, 0, stream>>>(x, wt, bq, bk, bv, q_ws, k_ws, vt_ws);
    attn_kernel<<<256, 256, 0, stream>>>(q_ws, k_ws, vt_ws, x, gamma, out);
}

// Round 2
// 114.011 us; speedup vs baseline: 3.3272x; 3.3272x over previous
//
#include <hip/hip_runtime.h>
#include <hip/hip_bf16.h>

typedef __attribute__((ext_vector_type(8))) short bf16x8;
typedef __attribute__((ext_vector_type(4))) float f32x4;
typedef __attribute__((ext_vector_type(4))) int int4v;

// Problem constants
#define NB 4
#define NN 4096
#define NC 256
#define NSPLIT 4
#define KEYS_PER_SPLIT 1024
#define KT_ITERS 16      // KEYS_PER_SPLIT / 64

__device__ __forceinline__ unsigned short f2bf(float f) {
    unsigned u = __builtin_bit_cast(unsigned, f);
    u += 0x7fffu + ((u >> 16) & 1u);   // round-to-nearest-even
    return (unsigned short)(u >> 16);
}
__device__ __forceinline__ float bf2f(unsigned short u) {
    unsigned v = ((unsigned)u) << 16;
    return __builtin_bit_cast(float, v);
}
__device__ __forceinline__ void load_lds16(const void* g, void* l) {
    __builtin_amdgcn_global_load_lds(
        (const __attribute__((address_space(1))) void*)g,
        (__attribute__((address_space(3))) void*)l, 16, 0, 0);
}

// ---------------- kernel 0: weight transpose + bf16 cast ----------------
__global__ __launch_bounds__(256) void wt_kernel(
    const float* __restrict__ wq, const float* __restrict__ wk,
    const float* __restrict__ wv, unsigned short* __restrict__ wt)
{
    const int c = blockIdx.x;     // 0..319
    const int k = threadIdx.x;    // 0..255
    float v;
    if (c < 32)      v = wq[k * 32 + c];
    else if (c < 64) v = wk[k * 32 + (c - 32)];
    else             v = wv[k * 256 + (c - 64)];
    wt[c * 256 + k] = f2bf(v);
}

// ---------------- kernel 1: QKV projection (MFMA, no LDS) ----------------
// 1024 blocks x 16 rows; 4 waves split the 20 output col-groups (5 each).
__global__ __launch_bounds__(256) void proj_kernel(
    const float* __restrict__ x,              // [16384][256]
    const unsigned short* __restrict__ wt,    // [320][256] = W^T bf16
    const float* __restrict__ bq, const float* __restrict__ bk,
    const float* __restrict__ bv,
    unsigned short* __restrict__ q_ws,
    unsigned short* __restrict__ k_ws,
    unsigned short* __restrict__ vt_ws)
{
    const int lane = threadIdx.x & 63;
    const int w    = threadIdx.x >> 6;
    const int l15  = lane & 15, hh = lane >> 4;
    const int m0   = blockIdx.x * 16;      // 16 rows per block
    const int ct0  = w * 5;                // this wave's 5 col-groups

    f32x4 acc[5];
    #pragma unroll
    for (int i = 0; i < 5; ++i) acc[i] = f32x4{0.f, 0.f, 0.f, 0.f};

    const float* xrow = x + (size_t)(m0 + l15) * 256 + hh * 8;
    #pragma unroll
    for (int ks = 0; ks < 8; ++ks) {
        float4 xa = ((const float4*)(xrow + ks * 32))[0];
        float4 xb = ((const float4*)(xrow + ks * 32))[1];
        bf16x8 afrag;
        afrag[0] = (short)f2bf(xa.x); afrag[1] = (short)f2bf(xa.y);
        afrag[2] = (short)f2bf(xa.z); afrag[3] = (short)f2bf(xa.w);
        afrag[4] = (short)f2bf(xb.x); afrag[5] = (short)f2bf(xb.y);
        afrag[6] = (short)f2bf(xb.z); afrag[7] = (short)f2bf(xb.w);
        #pragma unroll
        for (int c = 0; c < 5; ++c) {
            bf16x8 bfrag = *(const bf16x8*)(wt + (size_t)((ct0 + c) * 16 + l15) * 256 + ks * 32 + hh * 8);
            acc[c] = __builtin_amdgcn_mfma_f32_16x16x32_bf16(afrag, bfrag, acc[c], 0, 0, 0);
        }
    }

    const int b    = m0 >> 12;
    const int nloc = m0 & 4095;
    #pragma unroll
    for (int c = 0; c < 5; ++c) {
        const int ct = ct0 + c;
        const int c0 = ct * 16;
        float bias;
        if (c0 < 32)      bias = bq[c0 + l15];
        else if (c0 < 64) bias = bk[c0 - 32 + l15];
        else              bias = bv[c0 - 64 + l15];
        if (c0 < 64) {
            unsigned short* dst = (c0 < 32) ? q_ws : k_ws;
            const int cc = (c0 < 32) ? c0 : (c0 - 32);
            #pragma unroll
            for (int i = 0; i < 4; ++i)
                dst[(size_t)(m0 + hh * 4 + i) * 32 + cc + l15] = f2bf(acc[c][i] + bias);
        } else {
            const int cc = c0 - 64 + l15;
            #pragma unroll
            for (int i = 0; i < 4; i += 2) {
                unsigned lo = f2bf(acc[c][i]     + bias);
                unsigned hi = f2bf(acc[c][i + 1] + bias);
                *(unsigned*)(vt_ws + ((size_t)b * 256 + cc) * 4096 + nloc + hh * 4 + i)
                    = lo | (hi << 16);
            }
        }
    }
}

// ---------------- kernel 2: flash attention, 4-way key split ----------------
// grid = 1024: split (4) x batch (4) x q-tile (64).  Block: 64 q-rows, 1024 keys.
// Waves: (wq, wc) 2x2.  QK: rows wq*32..+32, keys wc*32..+32 (no duplication).
// PV: rows wq*32..+32, cols wc*128..+128.  No max tracking (e is tiny).
__global__ __launch_bounds__(256, 3) void attn_kernel(
    const unsigned short* __restrict__ q_ws,
    const unsigned short* __restrict__ k_ws,
    const unsigned short* __restrict__ vt_ws,
    unsigned short* __restrict__ opart,   // [4][4][4096][256] bf16 (unnormalized)
    float* __restrict__ lpart)            // [4][4][4096] f32
{
    __shared__ unsigned short vt_lds[256 * 64];  // [c][key], 128B rows, XOR-swizzled
    __shared__ unsigned short p_lds[64 * 64];    // [qrow][key], swizzled
    __shared__ float l_red[2][64];

    const int lane = threadIdx.x & 63;
    const int wid  = threadIdx.x >> 6;
    const int l15  = lane & 15, hh = lane >> 4;
    const int split = blockIdx.x >> 8;
    const int rem   = blockIdx.x & 255;
    const int b     = rem >> 6;
    const int q0    = (rem & 63) * 64;
    const int wq    = wid >> 1;
    const int wc    = wid & 1;
    const int key0  = split * KEYS_PER_SPLIT;

    // persistent Q A-frags (rows wq*32 + qt*16 + l15)
    bf16x8 aq[2];
    #pragma unroll
    for (int qt = 0; qt < 2; ++qt)
        aq[qt] = *(const bf16x8*)(q_ws + (size_t)(b * 4096 + q0 + wq * 32 + qt * 16 + l15) * 32 + hh * 8);

    f32x4 acc[2][8];
    float lsum[2][4];
    #pragma unroll
    for (int qt = 0; qt < 2; ++qt) {
        #pragma unroll
        for (int ct = 0; ct < 8; ++ct) acc[qt][ct] = f32x4{0.f, 0.f, 0.f, 0.f};
        #pragma unroll
        for (int i = 0; i < 4; ++i) lsum[qt][i] = 0.f;
    }

    const unsigned short* vt_base = vt_ws + (size_t)b * 256 * 4096;
    const unsigned short* k_base  = k_ws + (size_t)b * 4096 * 32;

    for (int kt = 0; kt < KT_ITERS; ++kt) {
        const int kb = key0 + kt * 64;
        __syncthreads();   // prev iter's LDS reads complete

        // ---- async stage V^T tile (32KB), linear LDS dest + pre-swizzled src ----
        #pragma unroll
        for (int e = 0; e < 8; ++e) {
            int idx  = e * 256 + threadIdx.x;    // 16B chunk id
            int c    = idx >> 3;
            int slot = idx & 7;
            const unsigned short* src = vt_base + (size_t)c * 4096 + kb + ((slot ^ (c & 7)) << 3);
            load_lds16(src, (char*)vt_lds + idx * 16);
        }

        // ---- QK for this wave's (rows, key-half) ----
        bf16x8 bkf[2];
        #pragma unroll
        for (int g = 0; g < 2; ++g)
            bkf[g] = *(const bf16x8*)(k_base + (size_t)(kb + wc * 32 + g * 16 + l15) * 32 + hh * 8);
        f32x4 e2[2][2];
        #pragma unroll
        for (int qt = 0; qt < 2; ++qt) {
            #pragma unroll
            for (int g = 0; g < 2; ++g) {
                f32x4 z = {0.f, 0.f, 0.f, 0.f};
                e2[qt][g] = __builtin_amdgcn_mfma_f32_16x16x32_bf16(aq[qt], bkf[g], z, 0, 0, 0);
            }
        }

        // ---- p = exp(e), write P (swizzled), accumulate l ----
        #pragma unroll
        for (int qt = 0; qt < 2; ++qt) {
            #pragma unroll
            for (int g = 0; g < 2; ++g) {
                #pragma unroll
                for (int i = 0; i < 4; ++i) {
                    float p = __expf(e2[qt][g][i]);
                    lsum[qt][i] += p;
                    int r   = wq * 32 + qt * 16 + hh * 4 + i;
                    int off = (wc * 32 + g * 16 + l15) * 2;
                    int sw  = (((off >> 4) ^ (r & 7)) << 4) | (off & 15);
                    *(unsigned short*)((char*)p_lds + r * 128 + sw) = f2bf(p);
                }
            }
        }
        __syncthreads();   // V staged (vmcnt drained) + P visible

        // ---- PV: acc[qt][ct] += P[rows][keys] * V[keys][cols] ----
        #pragma unroll
        for (int s = 0; s < 2; ++s) {
            bf16x8 ap[2];
            #pragma unroll
            for (int qt = 0; qt < 2; ++qt) {
                int r = wq * 32 + qt * 16 + l15;
                ap[qt] = *(const bf16x8*)((char*)p_lds + r * 128 + (((s * 4 + hh) ^ (r & 7)) << 4));
            }
            #pragma unroll
            for (int ct = 0; ct < 8; ++ct) {
                int c = wc * 128 + ct * 16 + l15;
                bf16x8 bvf = *(const bf16x8*)((char*)vt_lds + c * 128 + (((s * 4 + hh) ^ (c & 7)) << 4));
                #pragma unroll
                for (int qt = 0; qt < 2; ++qt)
                    acc[qt][ct] = __builtin_amdgcn_mfma_f32_16x16x32_bf16(ap[qt], bvf, acc[qt][ct], 0, 0, 0);
            }
        }
    }

    // ---- epilogue: reduce l across lanes + wc pair; write partials ----
    __syncthreads();
    #pragma unroll
    for (int qt = 0; qt < 2; ++qt) {
        #pragma unroll
        for (int i = 0; i < 4; ++i) {
            float s = lsum[qt][i];
            s += __shfl_xor(s, 1); s += __shfl_xor(s, 2);
            s += __shfl_xor(s, 4); s += __shfl_xor(s, 8);
            if (l15 == 0) l_red[wc][wq * 32 + qt * 16 + hh * 4 + i] = s;
        }
    }
    __syncthreads();

    const size_t rowbase = (size_t)(split * 4 + b) * 4096 + q0;
    #pragma unroll
    for (int qt = 0; qt < 2; ++qt) {
        #pragma unroll
        for (int i = 0; i < 4; ++i) {
            int r = wq * 32 + qt * 16 + hh * 4 + i;
            if (wc == 0 && l15 == 0) {
                float lt = l_red[0][r] + l_red[1][r];
                lpart[rowbase + r] = lt;
            }
            #pragma unroll
            for (int ct = 0; ct < 8; ++ct) {
                int c = wc * 128 + ct * 16 + l15;
                opart[(rowbase + r) * 256 + c] = f2bf(acc[qt][ct][i]);
            }
        }
    }
}

// ---------------- kernel 3: combine splits + residual ----------------
__global__ __launch_bounds__(256) void combine_kernel(
    const unsigned short* __restrict__ opart,
    const float* __restrict__ lpart,
    const float* __restrict__ x,
    const float* __restrict__ gamma_p,
    float* __restrict__ out)
{
    const int t  = blockIdx.x * 256 + threadIdx.x;   // 0..524287
    const int r  = t >> 5;                           // global row 0..16383
    const int c0 = (t & 31) * 8;
    const float gamma = gamma_p[0];

    float sumO[8];
    #pragma unroll
    for (int j = 0; j < 8; ++j) sumO[j] = 0.f;
    float suml = 0.f;
    #pragma unroll
    for (int s = 0; s < NSPLIT; ++s) {
        bf16x8 o = *(const bf16x8*)(opart + ((size_t)(s * 16384 + r)) * 256 + c0);
        #pragma unroll
        for (int j = 0; j < 8; ++j) sumO[j] += bf2f((unsigned short)o[j]);
        suml += lpart[s * 16384 + r];
    }
    const float inv = gamma / suml;
    const size_t base = (size_t)r * 256 + c0;
    float4 x0 = *(const float4*)(x + base);
    float4 x1 = *(const float4*)(x + base + 4);
    float4 o0, o1;
    o0.x = sumO[0] * inv + x0.x; o0.y = sumO[1] * inv + x0.y;
    o0.z = sumO[2] * inv + x0.z; o0.w = sumO[3] * inv + x0.w;
    o1.x = sumO[4] * inv + x1.x; o1.y = sumO[5] * inv + x1.y;
    o1.z = sumO[6] * inv + x1.z; o1.w = sumO[7] * inv + x1.w;
    *(float4*)(out + base)     = o0;
    *(float4*)(out + base + 4) = o1;
}

extern "C" void kernel_launch(void* const* d_in, const int* in_sizes, int n_in,
                              void* d_out, int out_size, void* d_ws, size_t ws_size,
                              hipStream_t stream) {
    const float* x     = (const float*)d_in[0];
    const float* wq    = (const float*)d_in[1];
    const float* bq    = (const float*)d_in[2];
    const float* wk    = (const float*)d_in[3];
    const float* bk    = (const float*)d_in[4];
    const float* wv    = (const float*)d_in[5];
    const float* bv    = (const float*)d_in[6];
    const float* gamma = (const float*)d_in[7];
    float* out = (float*)d_out;

    char* ws = (char*)d_ws;
    unsigned short* wt    = (unsigned short*)(ws);                  // 160KB
    unsigned short* q_ws  = (unsigned short*)(ws + 163840);         // 1MB
    unsigned short* k_ws  = (unsigned short*)(ws + 1212416);        // 1MB
    unsigned short* vt_ws = (unsigned short*)(ws + 2260992);        // 8MB
    unsigned short* opart = (unsigned short*)(ws + 10649600);       // 32MB
    float*          lpart = (float*)(ws + 44204032);                // 256KB

    wt_kernel     <<<320,  256, 0, stream>>>(wq, wk, wv, wt);
    proj_kernel   <<<1024, 256, 0, stream>>>(x, wt, bq, bk, bv, q_ws, k_ws, vt_ws);
    attn_kernel   <<<1024, 256, 0, stream>>>(q_ws, k_ws, vt_ws, opart, lpart);
    combine_kernel<<<2048, 256, 0, stream>>>(opart, lpart, x, gamma, out);
}